// Round 1
// baseline (686.893 us; speedup 1.0000x reference)
//
#include <hip/hip_runtime.h>
#include <hip/hip_bf16.h>

#define HEADS 8
#define EPS_BN 1e-5f
#define NEG_SLOPE 0.2f
#define MAXDEG 192

// ---------------- CSR build ----------------

__global__ void count_kernel(const int* __restrict__ ei, int E, int N, int* __restrict__ counts) {
    int i = blockIdx.x * blockDim.x + threadIdx.x;
    int total = E + N;
    if (i >= total) return;
    int d = (i < E) ? ei[E + i] : (i - E);
    atomicAdd(&counts[d], 1);
}

__global__ __launch_bounds__(1024) void scan_kernel(const int* __restrict__ counts, int* __restrict__ offs, int n) {
    __shared__ int tile[1024];
    int tid = threadIdx.x;
    int carry = 0;
    for (int base = 0; base < n; base += 1024) {
        int v = (base + tid < n) ? counts[base + tid] : 0;
        tile[tid] = v;
        __syncthreads();
        for (int off = 1; off < 1024; off <<= 1) {
            int t = (tid >= off) ? tile[tid - off] : 0;
            __syncthreads();
            tile[tid] += t;
            __syncthreads();
        }
        if (base + tid < n) offs[base + tid + 1] = carry + tile[tid];
        carry += tile[1023];
        __syncthreads();
    }
    if (tid == 0) offs[0] = 0;
}

__global__ void scatter_kernel(const int* __restrict__ ei, int E, int N,
                               const int* __restrict__ offs, int* __restrict__ cursor,
                               int* __restrict__ csr_src) {
    int i = blockIdx.x * blockDim.x + threadIdx.x;
    int total = E + N;
    if (i >= total) return;
    int s, d;
    if (i < E) { s = ei[i]; d = ei[E + i]; } else { s = i - E; d = i - E; }
    int slot = atomicAdd(&cursor[d], 1);
    csr_src[offs[d] + slot] = s;
}

// ---------------- Linear layers ----------------

__global__ void linear1_kernel(const float* __restrict__ x, const float* __restrict__ W,
                               float* __restrict__ h, int N) {
    int i = blockIdx.x * blockDim.x + threadIdx.x;
    if (i >= N * 128) return;
    int n = i >> 7, f = i & 127;
    float acc = x[n * 3 + 0] * W[f] + x[n * 3 + 1] * W[128 + f] + x[n * 3 + 2] * W[256 + f];
    h[i] = acc;
}

template<int CIN, int F>
__global__ __launch_bounds__(256) void linear_kernel(const float* __restrict__ x,
                                                     const float* __restrict__ W,
                                                     float* __restrict__ h, int N) {
    constexpr int TN = 16;
    constexpr int NF = F / 256;
    __shared__ float xs[TN * CIN];
    int n0 = blockIdx.x * TN;
    // load x tile (16 consecutive rows are contiguous)
    for (int idx = threadIdx.x; idx < TN * CIN; idx += 256) {
        int gidx = n0 * CIN + idx;
        xs[idx] = (gidx < N * CIN) ? x[gidx] : 0.f;
    }
    __syncthreads();
    float acc[TN][NF];
#pragma unroll
    for (int i = 0; i < TN; ++i)
#pragma unroll
        for (int j = 0; j < NF; ++j) acc[i][j] = 0.f;

    for (int k = 0; k < CIN; ++k) {
        float w[NF];
#pragma unroll
        for (int j = 0; j < NF; ++j) w[j] = W[k * F + threadIdx.x + j * 256];
#pragma unroll
        for (int i = 0; i < TN; ++i) {
            float xv = xs[i * CIN + k];
#pragma unroll
            for (int j = 0; j < NF; ++j) acc[i][j] += xv * w[j];
        }
    }
#pragma unroll
    for (int i = 0; i < TN; ++i) {
        if (n0 + i < N) {
#pragma unroll
            for (int j = 0; j < NF; ++j)
                h[(n0 + i) * F + threadIdx.x + j * 256] = acc[i][j];
        }
    }
}

// ---------------- attention coefficients per node ----------------

template<int F, int C>
__global__ void al_kernel(const float* __restrict__ h, const float* __restrict__ a_s,
                          const float* __restrict__ a_d, float* __restrict__ als,
                          float* __restrict__ ald, int N) {
    int i = blockIdx.x * blockDim.x + threadIdx.x;
    if (i >= N * 8) return;
    int n = i >> 3, hh = i & 7;
    const float* hp = h + n * F + hh * C;
    const float* asp = a_s + hh * C;
    const float* adp = a_d + hh * C;
    float s = 0.f, dsum = 0.f;
#pragma unroll 4
    for (int c = 0; c < C; ++c) {
        float v = hp[c];
        s += v * asp[c];
        dsum += v * adp[c];
    }
    als[i] = s;
    ald[i] = dsum;
}

// ---------------- per-dst softmax + aggregation ----------------

template<int F, int C>
__global__ __launch_bounds__(F) void aggregate_kernel(const float* __restrict__ h,
                                                      const float* __restrict__ als,
                                                      const float* __restrict__ ald,
                                                      const int* __restrict__ offs,
                                                      const int* __restrict__ csr_src,
                                                      const float* __restrict__ bias,
                                                      float* __restrict__ out, int N) {
    __shared__ float wl[MAXDEG * 8];
    __shared__ int ssrc[MAXDEG];
    __shared__ float sm[8], sden[8], sald[8];
    int d = blockIdx.x;
    int start = offs[d];
    int deg = offs[d + 1] - start;
    int cdeg = (deg < MAXDEG) ? deg : MAXDEG;
    int tid = threadIdx.x;
    if (tid < 8) sald[tid] = ald[d * 8 + tid];
    for (int e = tid; e < cdeg; e += F) ssrc[e] = csr_src[start + e];
    __syncthreads();
    // logits
    for (int t = tid; t < cdeg * 8; t += F) {
        int e = t >> 3, hh = t & 7;
        float v = als[ssrc[e] * 8 + hh] + sald[hh];
        v = (v > 0.f) ? v : NEG_SLOPE * v;
        wl[t] = v;
    }
    __syncthreads();
    // per-head max + denom (serial over small degree, deterministic within call)
    if (tid < 8) {
        float m = -1e30f;
        for (int e = 0; e < cdeg; ++e) m = fmaxf(m, wl[e * 8 + tid]);
        for (int e = cdeg; e < deg; ++e) {
            int s = csr_src[start + e];
            float v = als[s * 8 + tid] + sald[tid];
            v = (v > 0.f) ? v : NEG_SLOPE * v;
            m = fmaxf(m, v);
        }
        float den = 0.f;
        for (int e = 0; e < cdeg; ++e) {
            float w = __expf(wl[e * 8 + tid] - m);
            wl[e * 8 + tid] = w;
            den += w;
        }
        for (int e = cdeg; e < deg; ++e) {
            int s = csr_src[start + e];
            float v = als[s * 8 + tid] + sald[tid];
            v = (v > 0.f) ? v : NEG_SLOPE * v;
            den += __expf(v - m);
        }
        sm[tid] = m;
        sden[tid] = den;
    }
    __syncthreads();
    // weighted gather
    int hf = tid / C;
    float inv = 1.0f / (sden[hf] + 1e-16f);
    float acc = 0.f;
    for (int e = 0; e < cdeg; ++e) {
        acc += wl[e * 8 + hf] * h[ssrc[e] * F + tid];
    }
    for (int e = cdeg; e < deg; ++e) {
        int s = csr_src[start + e];
        float v = als[s * 8 + hf] + sald[hf];
        v = (v > 0.f) ? v : NEG_SLOPE * v;
        acc += __expf(v - sm[hf]) * h[s * F + tid];
    }
    out[d * F + tid] = acc * inv + bias[tid];
}

// ---------------- BatchNorm + ReLU ----------------

template<int F>
__global__ __launch_bounds__(256) void bnstats_kernel(const float* __restrict__ x,
                                                      float* __restrict__ bnsum,
                                                      float* __restrict__ bnsq,
                                                      int N, int npb) {
    int n0 = blockIdx.x * npb;
    int n1 = n0 + npb;
    if (n1 > N) n1 = N;
    for (int f = threadIdx.x; f < F; f += 256) {
        float s = 0.f, sq = 0.f;
        for (int n = n0; n < n1; ++n) {
            float v = x[n * F + f];
            s += v;
            sq += v * v;
        }
        atomicAdd(&bnsum[f], s);
        atomicAdd(&bnsq[f], sq);
    }
}

template<int F>
__global__ void bnfin_kernel(const float* __restrict__ bnsum, const float* __restrict__ bnsq,
                             const float* __restrict__ g, const float* __restrict__ be,
                             float* __restrict__ scale, float* __restrict__ shift, int N) {
    int f = blockIdx.x * blockDim.x + threadIdx.x;
    if (f >= F) return;
    float invN = 1.0f / (float)N;
    float mean = bnsum[f] * invN;
    float var = bnsq[f] * invN - mean * mean;
    float sc = g[f] * rsqrtf(var + EPS_BN);
    scale[f] = sc;
    shift[f] = be[f] - mean * sc;
}

template<int F>
__global__ void bnrelu_kernel(float* __restrict__ x, const float* __restrict__ scale,
                              const float* __restrict__ shift, int total) {
    int i = blockIdx.x * blockDim.x + threadIdx.x;
    if (i >= total) return;
    int f = i & (F - 1);
    float v = x[i] * scale[f] + shift[f];
    x[i] = (v > 0.f) ? v : 0.f;
}

// ---------------- pooling + FC ----------------

__global__ __launch_bounds__(256) void pool_kernel(const float* __restrict__ x,
                                                   const int* __restrict__ batch,
                                                   float* __restrict__ pooled, int N) {
    int n0 = blockIdx.x * 64;
    int n1 = n0 + 64;
    if (n1 > N) n1 = N;
    int tid = threadIdx.x;
    float m0 = 0.f, m1 = 0.f;
    int cur = -1;
    for (int n = n0; n < n1; ++n) {
        int b = batch[n];
        if (b != cur) {
            if (cur >= 0) {
                atomicMax((int*)&pooled[cur * 512 + tid], __float_as_int(m0));
                atomicMax((int*)&pooled[cur * 512 + tid + 256], __float_as_int(m1));
            }
            cur = b;
            m0 = 0.f;
            m1 = 0.f;
        }
        m0 = fmaxf(m0, x[n * 512 + tid]);
        m1 = fmaxf(m1, x[n * 512 + tid + 256]);
    }
    if (cur >= 0) {
        atomicMax((int*)&pooled[cur * 512 + tid], __float_as_int(m0));
        atomicMax((int*)&pooled[cur * 512 + tid + 256], __float_as_int(m1));
    }
}

__global__ void fc_kernel(const float* __restrict__ pooled, const float* __restrict__ fcW,
                          const float* __restrict__ fcb, float* __restrict__ out) {
    int t = threadIdx.x;
    if (t >= 160) return;
    int b = t / 10, j = t % 10;
    float acc = fcb[j];
    for (int f = 0; f < 512; ++f) acc += pooled[b * 512 + f] * fcW[f * 10 + j];
    out[t] = acc;
}

// ---------------- launch ----------------

extern "C" void kernel_launch(void* const* d_in, const int* in_sizes, int n_in,
                              void* d_out, int out_size, void* d_ws, size_t ws_size,
                              hipStream_t stream) {
    const float* x   = (const float*)d_in[0];
    const int* ei    = (const int*)d_in[1];
    const int* batch = (const int*)d_in[2];
    const float* W1  = (const float*)d_in[3];
    const float* as1 = (const float*)d_in[4];
    const float* ad1 = (const float*)d_in[5];
    const float* b1  = (const float*)d_in[6];
    const float* g1  = (const float*)d_in[7];
    const float* be1 = (const float*)d_in[8];
    const float* W2  = (const float*)d_in[9];
    const float* as2 = (const float*)d_in[10];
    const float* ad2 = (const float*)d_in[11];
    const float* b2  = (const float*)d_in[12];
    const float* g2  = (const float*)d_in[13];
    const float* be2 = (const float*)d_in[14];
    const float* W3  = (const float*)d_in[15];
    const float* as3 = (const float*)d_in[16];
    const float* ad3 = (const float*)d_in[17];
    const float* b3  = (const float*)d_in[18];
    const float* g3  = (const float*)d_in[19];
    const float* be3 = (const float*)d_in[20];
    const float* fcW = (const float*)d_in[21];
    const float* fcb = (const float*)d_in[22];
    float* out = (float*)d_out;

    int N = in_sizes[0] / 3;
    int E = in_sizes[1] / 2;

    // workspace partition (256B aligned)
    char* p = (char*)d_ws;
    auto alloc = [&](size_t bytes) {
        char* r = p;
        p += (bytes + 255) & ~(size_t)255;
        return r;
    };
    int*   counts = (int*)alloc((size_t)N * 4);
    int*   offs   = (int*)alloc((size_t)(N + 1) * 4);
    int*   csr    = (int*)alloc((size_t)(E + N) * 4);
    float* h      = (float*)alloc((size_t)N * 512 * 4);
    float* agg    = (float*)alloc((size_t)N * 512 * 4);
    float* als    = (float*)alloc((size_t)N * 8 * 4);
    float* ald    = (float*)alloc((size_t)N * 8 * 4);
    float* bnsum  = (float*)alloc(512 * 4);
    float* bnsq   = (float*)alloc(512 * 4);
    float* scale  = (float*)alloc(512 * 4);
    float* shift  = (float*)alloc(512 * 4);
    float* pooled = (float*)alloc(16 * 512 * 4);

    int total_e = E + N;
    int npb = (N + 199) / 200;

    // ---- CSR build ----
    hipMemsetAsync(counts, 0, (size_t)N * 4, stream);
    count_kernel<<<(total_e + 255) / 256, 256, 0, stream>>>(ei, E, N, counts);
    scan_kernel<<<1, 1024, 0, stream>>>(counts, offs, N);
    hipMemsetAsync(counts, 0, (size_t)N * 4, stream);
    scatter_kernel<<<(total_e + 255) / 256, 256, 0, stream>>>(ei, E, N, offs, counts, csr);

    // ---- layer 1: 3 -> 8x16 (F=128) ----
    linear1_kernel<<<(N * 128 + 255) / 256, 256, 0, stream>>>(x, W1, h, N);
    al_kernel<128, 16><<<(N * 8 + 255) / 256, 256, 0, stream>>>(h, as1, ad1, als, ald, N);
    aggregate_kernel<128, 16><<<N, 128, 0, stream>>>(h, als, ald, offs, csr, b1, agg, N);
    hipMemsetAsync(bnsum, 0, 512 * 4, stream);
    hipMemsetAsync(bnsq, 0, 512 * 4, stream);
    bnstats_kernel<128><<<200, 256, 0, stream>>>(agg, bnsum, bnsq, N, npb);
    bnfin_kernel<128><<<1, 128, 0, stream>>>(bnsum, bnsq, g1, be1, scale, shift, N);
    bnrelu_kernel<128><<<(N * 128 + 255) / 256, 256, 0, stream>>>(agg, scale, shift, N * 128);

    // ---- layer 2: 128 -> 8x32 (F=256) ----
    linear_kernel<128, 256><<<(N + 15) / 16, 256, 0, stream>>>(agg, W2, h, N);
    al_kernel<256, 32><<<(N * 8 + 255) / 256, 256, 0, stream>>>(h, as2, ad2, als, ald, N);
    aggregate_kernel<256, 32><<<N, 256, 0, stream>>>(h, als, ald, offs, csr, b2, agg, N);
    hipMemsetAsync(bnsum, 0, 512 * 4, stream);
    hipMemsetAsync(bnsq, 0, 512 * 4, stream);
    bnstats_kernel<256><<<200, 256, 0, stream>>>(agg, bnsum, bnsq, N, npb);
    bnfin_kernel<256><<<1, 256, 0, stream>>>(bnsum, bnsq, g2, be2, scale, shift, N);
    bnrelu_kernel<256><<<(N * 256 + 255) / 256, 256, 0, stream>>>(agg, scale, shift, N * 256);

    // ---- layer 3: 256 -> 8x64 (F=512) ----
    linear_kernel<256, 512><<<(N + 15) / 16, 256, 0, stream>>>(agg, W3, h, N);
    al_kernel<512, 64><<<(N * 8 + 255) / 256, 256, 0, stream>>>(h, as3, ad3, als, ald, N);
    aggregate_kernel<512, 64><<<N, 512, 0, stream>>>(h, als, ald, offs, csr, b3, agg, N);
    hipMemsetAsync(bnsum, 0, 512 * 4, stream);
    hipMemsetAsync(bnsq, 0, 512 * 4, stream);
    bnstats_kernel<512><<<200, 256, 0, stream>>>(agg, bnsum, bnsq, N, npb);
    bnfin_kernel<512><<<1, 512, 0, stream>>>(bnsum, bnsq, g3, be3, scale, shift, N);
    bnrelu_kernel<512><<<(N * 512 + 255) / 256, 256, 0, stream>>>(agg, scale, shift, N * 512);

    // ---- pool + fc ----
    hipMemsetAsync(pooled, 0, 16 * 512 * 4, stream);
    pool_kernel<<<(N + 63) / 64, 256, 0, stream>>>(agg, batch, pooled, N);
    fc_kernel<<<1, 192, 0, stream>>>(pooled, fcW, fcb, out);
}

// Round 2
// 505.826 us; speedup vs baseline: 1.3580x; 1.3580x over previous
//
#include <hip/hip_runtime.h>
#include <hip/hip_bf16.h>

#define HEADS 8
#define EPS_BN 1e-5f
#define NEG_SLOPE 0.2f
#define MAXDEG 192

__device__ __forceinline__ float bf2f(unsigned short u) {
    return __uint_as_float(((unsigned int)u) << 16);
}

// ---------------- CSR build ----------------

__global__ void count_kernel(const int* __restrict__ ei, int E, int N, int* __restrict__ counts) {
    int i = blockIdx.x * blockDim.x + threadIdx.x;
    int total = E + N;
    if (i >= total) return;
    int d = (i < E) ? ei[E + i] : (i - E);
    atomicAdd(&counts[d], 1);
}

__global__ __launch_bounds__(1024) void scan_block_kernel(const int* __restrict__ counts,
                                                          int* __restrict__ offs,
                                                          int* __restrict__ part, int n) {
    __shared__ int tile[1024];
    int tid = threadIdx.x;
    int gid = blockIdx.x * 1024 + tid;
    int v = (gid < n) ? counts[gid] : 0;
    tile[tid] = v;
    __syncthreads();
    for (int off = 1; off < 1024; off <<= 1) {
        int t = (tid >= off) ? tile[tid - off] : 0;
        __syncthreads();
        tile[tid] += t;
        __syncthreads();
    }
    if (gid < n) offs[gid + 1] = tile[tid];
    if (tid == 1023) part[blockIdx.x] = tile[1023];
}

__global__ void scan_part_kernel(int* __restrict__ part, int nb) {
    if (threadIdx.x == 0) {
        int s = 0;
        for (int i = 0; i < nb; ++i) { int v = part[i]; part[i] = s; s += v; }
    }
}

__global__ __launch_bounds__(1024) void scan_add_kernel(int* __restrict__ offs,
                                                        const int* __restrict__ part, int n) {
    int gid = blockIdx.x * 1024 + threadIdx.x;
    if (gid < n) offs[gid + 1] += part[blockIdx.x];
    if (gid == 0) offs[0] = 0;
}

__global__ void scatter_kernel(const int* __restrict__ ei, int E, int N,
                               const int* __restrict__ offs, int* __restrict__ cursor,
                               int* __restrict__ csr_src) {
    int i = blockIdx.x * blockDim.x + threadIdx.x;
    int total = E + N;
    if (i >= total) return;
    int s, d;
    if (i < E) { s = ei[i]; d = ei[E + i]; } else { s = i - E; d = i - E; }
    int slot = atomicAdd(&cursor[d], 1);
    csr_src[offs[d] + slot] = s;
}

// ---------------- Linear layers ----------------

__global__ void linear1_kernel(const float* __restrict__ x, const float* __restrict__ W,
                               __hip_bfloat16* __restrict__ h, int N) {
    int i = blockIdx.x * blockDim.x + threadIdx.x;
    if (i >= N * 128) return;
    int n = i >> 7, f = i & 127;
    float acc = x[n * 3 + 0] * W[f] + x[n * 3 + 1] * W[128 + f] + x[n * 3 + 2] * W[256 + f];
    h[i] = __float2bfloat16(acc);
}

// x is PRE-BN aggregate output; scale/shift+relu applied at tile load.
template<int CIN, int F>
__global__ __launch_bounds__(256) void linear_kernel(const float* __restrict__ x,
                                                     const float* __restrict__ scale,
                                                     const float* __restrict__ shift,
                                                     const float* __restrict__ W,
                                                     __hip_bfloat16* __restrict__ h, int N) {
    constexpr int TN = 16;
    constexpr int NF = F / 256;
    __shared__ float xs[TN * CIN];
    int n0 = blockIdx.x * TN;
    for (int idx = threadIdx.x; idx < TN * CIN; idx += 256) {
        int gidx = n0 * CIN + idx;
        float v = 0.f;
        if (gidx < N * CIN) {
            int f = idx & (CIN - 1);
            v = x[gidx] * scale[f] + shift[f];
            v = (v > 0.f) ? v : 0.f;
        }
        xs[idx] = v;
    }
    __syncthreads();
    float acc[TN][NF];
#pragma unroll
    for (int i = 0; i < TN; ++i)
#pragma unroll
        for (int j = 0; j < NF; ++j) acc[i][j] = 0.f;

    for (int k = 0; k < CIN; ++k) {
        float w[NF];
#pragma unroll
        for (int j = 0; j < NF; ++j) w[j] = W[k * F + threadIdx.x + j * 256];
#pragma unroll
        for (int i = 0; i < TN; ++i) {
            float xv = xs[i * CIN + k];
#pragma unroll
            for (int j = 0; j < NF; ++j) acc[i][j] += xv * w[j];
        }
    }
#pragma unroll
    for (int i = 0; i < TN; ++i) {
        if (n0 + i < N) {
#pragma unroll
            for (int j = 0; j < NF; ++j)
                h[(size_t)(n0 + i) * F + threadIdx.x + j * 256] = __float2bfloat16(acc[i][j]);
        }
    }
}

// ---------------- attention coefficients per node ----------------

template<int F, int C>
__global__ void al_kernel(const __hip_bfloat16* __restrict__ h, const float* __restrict__ a_s,
                          const float* __restrict__ a_d, float* __restrict__ als,
                          float* __restrict__ ald, int N) {
    int i = blockIdx.x * blockDim.x + threadIdx.x;
    if (i >= N * 8) return;
    int n = i >> 3, hh = i & 7;
    const ushort* hp = (const ushort*)(h + (size_t)n * F + hh * C);
    const float* asp = a_s + hh * C;
    const float* adp = a_d + hh * C;
    float s = 0.f, dsum = 0.f;
#pragma unroll
    for (int c = 0; c < C; c += 4) {
        ushort4 u = *(const ushort4*)(hp + c);
        float v0 = bf2f(u.x), v1 = bf2f(u.y), v2 = bf2f(u.z), v3 = bf2f(u.w);
        s += v0 * asp[c] + v1 * asp[c + 1] + v2 * asp[c + 2] + v3 * asp[c + 3];
        dsum += v0 * adp[c] + v1 * adp[c + 1] + v2 * adp[c + 2] + v3 * adp[c + 3];
    }
    als[i] = s;
    ald[i] = dsum;
}

// ---------------- per-dst softmax + aggregation ----------------

template<int F, int C>
__global__ __launch_bounds__(F / 2) void aggregate_kernel(const __hip_bfloat16* __restrict__ h,
                                                          const float* __restrict__ als,
                                                          const float* __restrict__ ald,
                                                          const int* __restrict__ offs,
                                                          const int* __restrict__ csr_src,
                                                          const float* __restrict__ bias,
                                                          float* __restrict__ out, int N) {
    constexpr int T = F / 2;
    __shared__ float wl[MAXDEG * 8];
    __shared__ int ssrc[MAXDEG];
    __shared__ float sm[8], sden[8], sald[8];
    int d = blockIdx.x;
    int start = offs[d];
    int deg = offs[d + 1] - start;
    int cdeg = (deg < MAXDEG) ? deg : MAXDEG;
    int tid = threadIdx.x;
    if (tid < 8) sald[tid] = ald[d * 8 + tid];
    for (int e = tid; e < cdeg; e += T) ssrc[e] = csr_src[start + e];
    __syncthreads();
    // logits
    for (int t = tid; t < cdeg * 8; t += T) {
        int e = t >> 3, hh = t & 7;
        float v = als[ssrc[e] * 8 + hh] + sald[hh];
        v = (v > 0.f) ? v : NEG_SLOPE * v;
        wl[t] = v;
    }
    __syncthreads();
    // per-head max + denom
    if (tid < 8) {
        float m = -1e30f;
        for (int e = 0; e < cdeg; ++e) m = fmaxf(m, wl[e * 8 + tid]);
        for (int e = cdeg; e < deg; ++e) {
            int s = csr_src[start + e];
            float v = als[s * 8 + tid] + sald[tid];
            v = (v > 0.f) ? v : NEG_SLOPE * v;
            m = fmaxf(m, v);
        }
        float den = 0.f;
        for (int e = 0; e < cdeg; ++e) {
            float w = __expf(wl[e * 8 + tid] - m);
            wl[e * 8 + tid] = w;
            den += w;
        }
        for (int e = cdeg; e < deg; ++e) {
            int s = csr_src[start + e];
            float v = als[s * 8 + tid] + sald[tid];
            v = (v > 0.f) ? v : NEG_SLOPE * v;
            den += __expf(v - m);
        }
        sm[tid] = m;
        sden[tid] = den;
    }
    __syncthreads();
    // weighted gather: thread -> 2 consecutive cols
    int hf = tid / (C / 2);
    float inv = 1.0f / (sden[hf] + 1e-16f);
    float acc0 = 0.f, acc1 = 0.f;
    for (int e = 0; e < cdeg; ++e) {
        float w = wl[e * 8 + hf];
        ushort2 u = *(const ushort2*)((const ushort*)h + (size_t)ssrc[e] * F + 2 * tid);
        acc0 += w * bf2f(u.x);
        acc1 += w * bf2f(u.y);
    }
    for (int e = cdeg; e < deg; ++e) {
        int s = csr_src[start + e];
        float v = als[s * 8 + hf] + sald[hf];
        v = (v > 0.f) ? v : NEG_SLOPE * v;
        float w = __expf(v - sm[hf]);
        ushort2 u = *(const ushort2*)((const ushort*)h + (size_t)s * F + 2 * tid);
        acc0 += w * bf2f(u.x);
        acc1 += w * bf2f(u.y);
    }
    out[(size_t)d * F + 2 * tid]     = acc0 * inv + bias[2 * tid];
    out[(size_t)d * F + 2 * tid + 1] = acc1 * inv + bias[2 * tid + 1];
}

// ---------------- BatchNorm ----------------

template<int F>
__global__ __launch_bounds__(256) void bnstats_kernel(const float* __restrict__ x,
                                                      float* __restrict__ bnsum,
                                                      float* __restrict__ bnsq,
                                                      int N, int npb) {
    int n0 = blockIdx.x * npb;
    int n1 = n0 + npb;
    if (n1 > N) n1 = N;
    for (int f = threadIdx.x; f < F; f += 256) {
        float s = 0.f, sq = 0.f;
        for (int n = n0; n < n1; ++n) {
            float v = x[(size_t)n * F + f];
            s += v;
            sq += v * v;
        }
        atomicAdd(&bnsum[f], s);
        atomicAdd(&bnsq[f], sq);
    }
}

template<int F>
__global__ void bnfin_kernel(const float* __restrict__ bnsum, const float* __restrict__ bnsq,
                             const float* __restrict__ g, const float* __restrict__ be,
                             float* __restrict__ scale, float* __restrict__ shift, int N) {
    int f = blockIdx.x * blockDim.x + threadIdx.x;
    if (f >= F) return;
    float invN = 1.0f / (float)N;
    float mean = bnsum[f] * invN;
    float var = bnsq[f] * invN - mean * mean;
    float sc = g[f] * rsqrtf(var + EPS_BN);
    scale[f] = sc;
    shift[f] = be[f] - mean * sc;
}

// ---------------- pooling + FC (BN3+ReLU fused into pool) ----------------

__global__ __launch_bounds__(256) void pool_kernel(const float* __restrict__ x,
                                                   const int* __restrict__ batch,
                                                   const float* __restrict__ scale,
                                                   const float* __restrict__ shift,
                                                   float* __restrict__ pooled, int N) {
    int n0 = blockIdx.x * 64;
    int n1 = n0 + 64;
    if (n1 > N) n1 = N;
    int tid = threadIdx.x;
    float sc0 = scale[tid], sh0 = shift[tid];
    float sc1 = scale[tid + 256], sh1 = shift[tid + 256];
    float m0 = 0.f, m1 = 0.f;
    int cur = -1;
    for (int n = n0; n < n1; ++n) {
        int b = batch[n];
        if (b != cur) {
            if (cur >= 0) {
                atomicMax((int*)&pooled[cur * 512 + tid], __float_as_int(m0));
                atomicMax((int*)&pooled[cur * 512 + tid + 256], __float_as_int(m1));
            }
            cur = b;
            m0 = 0.f;
            m1 = 0.f;
        }
        float v0 = x[(size_t)n * 512 + tid] * sc0 + sh0;
        float v1 = x[(size_t)n * 512 + tid + 256] * sc1 + sh1;
        m0 = fmaxf(m0, v0);
        m1 = fmaxf(m1, v1);
    }
    if (cur >= 0) {
        atomicMax((int*)&pooled[cur * 512 + tid], __float_as_int(m0));
        atomicMax((int*)&pooled[cur * 512 + tid + 256], __float_as_int(m1));
    }
}

__global__ void fc_kernel(const float* __restrict__ pooled, const float* __restrict__ fcW,
                          const float* __restrict__ fcb, float* __restrict__ out) {
    int t = threadIdx.x;
    if (t >= 160) return;
    int b = t / 10, j = t % 10;
    float acc = fcb[j];
    for (int f = 0; f < 512; ++f) acc += pooled[b * 512 + f] * fcW[f * 10 + j];
    out[t] = acc;
}

// ---------------- launch ----------------

extern "C" void kernel_launch(void* const* d_in, const int* in_sizes, int n_in,
                              void* d_out, int out_size, void* d_ws, size_t ws_size,
                              hipStream_t stream) {
    const float* x   = (const float*)d_in[0];
    const int* ei    = (const int*)d_in[1];
    const int* batch = (const int*)d_in[2];
    const float* W1  = (const float*)d_in[3];
    const float* as1 = (const float*)d_in[4];
    const float* ad1 = (const float*)d_in[5];
    const float* b1  = (const float*)d_in[6];
    const float* g1  = (const float*)d_in[7];
    const float* be1 = (const float*)d_in[8];
    const float* W2  = (const float*)d_in[9];
    const float* as2 = (const float*)d_in[10];
    const float* ad2 = (const float*)d_in[11];
    const float* b2  = (const float*)d_in[12];
    const float* g2  = (const float*)d_in[13];
    const float* be2 = (const float*)d_in[14];
    const float* W3  = (const float*)d_in[15];
    const float* as3 = (const float*)d_in[16];
    const float* ad3 = (const float*)d_in[17];
    const float* b3  = (const float*)d_in[18];
    const float* g3  = (const float*)d_in[19];
    const float* be3 = (const float*)d_in[20];
    const float* fcW = (const float*)d_in[21];
    const float* fcb = (const float*)d_in[22];
    float* out = (float*)d_out;

    int N = in_sizes[0] / 3;
    int E = in_sizes[1] / 2;

    char* p = (char*)d_ws;
    auto alloc = [&](size_t bytes) {
        char* r = p;
        p += (bytes + 255) & ~(size_t)255;
        return r;
    };
    int*   counts = (int*)alloc((size_t)N * 4);
    int*   offs   = (int*)alloc((size_t)(N + 1) * 4);
    int*   part   = (int*)alloc(64 * 4);
    int*   csr    = (int*)alloc((size_t)(E + N) * 4);
    __hip_bfloat16* h = (__hip_bfloat16*)alloc((size_t)N * 512 * 2);
    float* agg    = (float*)alloc((size_t)N * 512 * 4);
    float* als    = (float*)alloc((size_t)N * 8 * 4);
    float* ald    = (float*)alloc((size_t)N * 8 * 4);
    float* bnsum  = (float*)alloc(512 * 4);
    float* bnsq   = (float*)alloc(512 * 4);
    float* scale  = (float*)alloc(512 * 4);
    float* shift  = (float*)alloc(512 * 4);
    float* pooled = (float*)alloc(16 * 512 * 4);

    int total_e = E + N;
    int npb = (N + 199) / 200;
    int nchunks = (N + 1023) / 1024;

    // ---- CSR build ----
    hipMemsetAsync(counts, 0, (size_t)N * 4, stream);
    count_kernel<<<(total_e + 255) / 256, 256, 0, stream>>>(ei, E, N, counts);
    scan_block_kernel<<<nchunks, 1024, 0, stream>>>(counts, offs, part, N);
    scan_part_kernel<<<1, 64, 0, stream>>>(part, nchunks);
    scan_add_kernel<<<nchunks, 1024, 0, stream>>>(offs, part, N);
    hipMemsetAsync(counts, 0, (size_t)N * 4, stream);
    scatter_kernel<<<(total_e + 255) / 256, 256, 0, stream>>>(ei, E, N, offs, counts, csr);

    // ---- layer 1: 3 -> 8x16 (F=128) ----
    linear1_kernel<<<(N * 128 + 255) / 256, 256, 0, stream>>>(x, W1, h, N);
    al_kernel<128, 16><<<(N * 8 + 255) / 256, 256, 0, stream>>>(h, as1, ad1, als, ald, N);
    aggregate_kernel<128, 16><<<N, 64, 0, stream>>>(h, als, ald, offs, csr, b1, agg, N);
    hipMemsetAsync(bnsum, 0, 512 * 4, stream);
    hipMemsetAsync(bnsq, 0, 512 * 4, stream);
    bnstats_kernel<128><<<200, 256, 0, stream>>>(agg, bnsum, bnsq, N, npb);
    bnfin_kernel<128><<<1, 128, 0, stream>>>(bnsum, bnsq, g1, be1, scale, shift, N);

    // ---- layer 2: 128 -> 8x32 (F=256), BN1+ReLU fused into tile load ----
    linear_kernel<128, 256><<<(N + 15) / 16, 256, 0, stream>>>(agg, scale, shift, W2, h, N);
    al_kernel<256, 32><<<(N * 8 + 255) / 256, 256, 0, stream>>>(h, as2, ad2, als, ald, N);
    aggregate_kernel<256, 32><<<N, 128, 0, stream>>>(h, als, ald, offs, csr, b2, agg, N);
    hipMemsetAsync(bnsum, 0, 512 * 4, stream);
    hipMemsetAsync(bnsq, 0, 512 * 4, stream);
    bnstats_kernel<256><<<200, 256, 0, stream>>>(agg, bnsum, bnsq, N, npb);
    bnfin_kernel<256><<<1, 256, 0, stream>>>(bnsum, bnsq, g2, be2, scale, shift, N);

    // ---- layer 3: 256 -> 8x64 (F=512), BN2+ReLU fused ----
    linear_kernel<256, 512><<<(N + 15) / 16, 256, 0, stream>>>(agg, scale, shift, W3, h, N);
    al_kernel<512, 64><<<(N * 8 + 255) / 256, 256, 0, stream>>>(h, as3, ad3, als, ald, N);
    aggregate_kernel<512, 64><<<N, 256, 0, stream>>>(h, als, ald, offs, csr, b3, agg, N);
    hipMemsetAsync(bnsum, 0, 512 * 4, stream);
    hipMemsetAsync(bnsq, 0, 512 * 4, stream);
    bnstats_kernel<512><<<200, 256, 0, stream>>>(agg, bnsum, bnsq, N, npb);
    bnfin_kernel<512><<<1, 512, 0, stream>>>(bnsum, bnsq, g3, be3, scale, shift, N);

    // ---- pool (BN3+ReLU fused) + fc ----
    hipMemsetAsync(pooled, 0, 16 * 512 * 4, stream);
    pool_kernel<<<(N + 63) / 64, 256, 0, stream>>>(agg, batch, scale, shift, pooled, N);
    fc_kernel<<<1, 192, 0, stream>>>(pooled, fcW, fcb, out);
}

// Round 3
// 421.184 us; speedup vs baseline: 1.6309x; 1.2010x over previous
//
#include <hip/hip_runtime.h>
#include <hip/hip_bf16.h>

#define HEADS 8
#define EPS_BN 1e-5f
#define NEG_SLOPE 0.2f
#define MAXDEG 192

typedef __attribute__((ext_vector_type(8))) short bf16x8;
typedef __attribute__((ext_vector_type(4))) float f32x4;

__device__ __forceinline__ float bf2f(unsigned short u) {
    return __uint_as_float(((unsigned int)u) << 16);
}

__device__ __forceinline__ unsigned short f2bf(float f) {
    __hip_bfloat16 b = __float2bfloat16(f);
    return *reinterpret_cast<unsigned short*>(&b);
}

__device__ __forceinline__ void gld_lds16(const ushort* g, ushort* l) {
    __builtin_amdgcn_global_load_lds(
        (const __attribute__((address_space(1))) unsigned int*)g,
        (__attribute__((address_space(3))) unsigned int*)l, 16, 0, 0);
}

// ---------------- CSR build ----------------

__global__ void count_kernel(const int* __restrict__ ei, int E, int N, int* __restrict__ counts) {
    int i = blockIdx.x * blockDim.x + threadIdx.x;
    int total = E + N;
    if (i >= total) return;
    int d = (i < E) ? ei[E + i] : (i - E);
    atomicAdd(&counts[d], 1);
}

__global__ __launch_bounds__(1024) void scan_block_kernel(const int* __restrict__ counts,
                                                          int* __restrict__ offs,
                                                          int* __restrict__ part, int n) {
    __shared__ int tile[1024];
    int tid = threadIdx.x;
    int gid = blockIdx.x * 1024 + tid;
    int v = (gid < n) ? counts[gid] : 0;
    tile[tid] = v;
    __syncthreads();
    for (int off = 1; off < 1024; off <<= 1) {
        int t = (tid >= off) ? tile[tid - off] : 0;
        __syncthreads();
        tile[tid] += t;
        __syncthreads();
    }
    if (gid < n) offs[gid + 1] = tile[tid];
    if (tid == 1023) part[blockIdx.x] = tile[1023];
}

__global__ void scan_part_kernel(int* __restrict__ part, int nb) {
    if (threadIdx.x == 0) {
        int s = 0;
        for (int i = 0; i < nb; ++i) { int v = part[i]; part[i] = s; s += v; }
    }
}

__global__ __launch_bounds__(1024) void scan_add_kernel(int* __restrict__ offs,
                                                        const int* __restrict__ part, int n) {
    int gid = blockIdx.x * 1024 + threadIdx.x;
    if (gid < n) offs[gid + 1] += part[blockIdx.x];
    if (gid == 0) offs[0] = 0;
}

__global__ void scatter_kernel(const int* __restrict__ ei, int E, int N,
                               const int* __restrict__ offs, int* __restrict__ cursor,
                               int* __restrict__ csr_src) {
    int i = blockIdx.x * blockDim.x + threadIdx.x;
    int total = E + N;
    if (i >= total) return;
    int s, d;
    if (i < E) { s = ei[i]; d = ei[E + i]; } else { s = i - E; d = i - E; }
    int slot = atomicAdd(&cursor[d], 1);
    csr_src[offs[d] + slot] = s;
}

// ---------------- layer-1 linear (trivial, 3->128) ----------------

__global__ void linear1_kernel(const float* __restrict__ x, const float* __restrict__ W,
                               __hip_bfloat16* __restrict__ h, int N) {
    int i = blockIdx.x * blockDim.x + threadIdx.x;
    if (i >= N * 128) return;
    int n = i >> 7, f = i & 127;
    float acc = x[n * 3 + 0] * W[f] + x[n * 3 + 1] * W[128 + f] + x[n * 3 + 2] * W[256 + f];
    h[i] = __float2bfloat16(acc);
}

// ---------------- W transpose to [N][K] bf16 ----------------

__global__ __launch_bounds__(256) void transpose_w_kernel(const float* __restrict__ W,
                                                          ushort* __restrict__ Wt,
                                                          int K, int Nc) {
    __shared__ float t[32][33];
    int nb = Nc / 32;
    int bx = blockIdx.x % nb, by = blockIdx.x / nb;
    int n0 = bx * 32, k0 = by * 32;
    int lx = threadIdx.x & 31, ly = threadIdx.x >> 5;
    for (int r = ly; r < 32; r += 8) t[r][lx] = W[(size_t)(k0 + r) * Nc + n0 + lx];
    __syncthreads();
    for (int r = ly; r < 32; r += 8) Wt[(size_t)(n0 + r) * K + k0 + lx] = f2bf(t[lx][r]);
}

// ---------------- BN apply + ReLU + bf16 pack (GEMM A prep) ----------------

template<int F>
__global__ void prep_kernel(const float4* __restrict__ x, const float* __restrict__ scale,
                            const float* __restrict__ shift, ushort4* __restrict__ A, int n4) {
    int i = blockIdx.x * blockDim.x + threadIdx.x;
    if (i >= n4) return;
    float4 v = x[i];
    int f = (i << 2) & (F - 1);
    float4 sc = *(const float4*)(scale + f);
    float4 sh = *(const float4*)(shift + f);
    ushort4 u;
    u.x = f2bf(fmaxf(v.x * sc.x + sh.x, 0.f));
    u.y = f2bf(fmaxf(v.y * sc.y + sh.y, 0.f));
    u.z = f2bf(fmaxf(v.z * sc.z + sh.z, 0.f));
    u.w = f2bf(fmaxf(v.w * sc.w + sh.w, 0.f));
    A[i] = u;
}

// ---------------- MFMA bf16 GEMM: C[M][Nc] = A[M][K] * Bt[Nc][K]^T ----------------
// 128x128 tile, BK=64, 4 waves (2x2), each wave 64x64 (4x4 frags of 16x16x32).

template<int K>
__global__ __launch_bounds__(256) void mfma_gemm_kernel(const ushort* __restrict__ A,
                                                        const ushort* __restrict__ Bt,
                                                        ushort* __restrict__ C,
                                                        int M, int Ncols) {
    __shared__ __align__(16) ushort lA[128 * 64];
    __shared__ __align__(16) ushort lB[128 * 64];
    int tid = threadIdx.x;
    int l = tid & 63, w = tid >> 6;
    int m0 = blockIdx.x * 128;
    int n0 = blockIdx.y * 128;
    int wm = w >> 1, wn = w & 1;
    f32x4 zero = {0.f, 0.f, 0.f, 0.f};
    f32x4 acc[4][4];
#pragma unroll
    for (int m = 0; m < 4; ++m)
#pragma unroll
        for (int n = 0; n < 4; ++n) acc[m][n] = zero;

#pragma unroll
    for (int k0 = 0; k0 < K; k0 += 64) {
        if (k0) __syncthreads();
        // stage A,B tiles: 1024 chunks of 16B each; LDS linear, global pre-swizzled
#pragma unroll
        for (int i = 0; i < 4; ++i) {
            int idx = (w * 4 + i) * 64 + l;
            int row = idx >> 3, p = idx & 7;
            int gc = (p ^ (row & 7)) * 8;            // element offset in 64-wide K slice
            int ar = m0 + row; ar = (ar < M) ? ar : (M - 1);
            gld_lds16(A + (size_t)ar * K + k0 + gc, &lA[idx * 8]);
            gld_lds16(Bt + (size_t)(n0 + row) * K + k0 + gc, &lB[idx * 8]);
        }
        __syncthreads();   // compiler drains vmcnt(0) before barrier
#pragma unroll
        for (int ks = 0; ks < 2; ++ks) {
            bf16x8 af[4], bfr[4];
#pragma unroll
            for (int m = 0; m < 4; ++m) {
                int row = wm * 64 + m * 16 + (l & 15);
                int cp = (ks * 4 + (l >> 4)) ^ (row & 7);
                af[m] = *(const bf16x8*)&lA[row * 64 + cp * 8];
            }
#pragma unroll
            for (int n = 0; n < 4; ++n) {
                int row = wn * 64 + n * 16 + (l & 15);
                int cp = (ks * 4 + (l >> 4)) ^ (row & 7);
                bfr[n] = *(const bf16x8*)&lB[row * 64 + cp * 8];
            }
#pragma unroll
            for (int m = 0; m < 4; ++m)
#pragma unroll
                for (int n = 0; n < 4; ++n)
                    acc[m][n] = __builtin_amdgcn_mfma_f32_16x16x32_bf16(af[m], bfr[n], acc[m][n], 0, 0, 0);
        }
    }
    int lr = (l >> 4) * 4, lc = l & 15;
#pragma unroll
    for (int m = 0; m < 4; ++m) {
#pragma unroll
        for (int q = 0; q < 4; ++q) {
            int r = m0 + wm * 64 + m * 16 + lr + q;
            if (r < M) {
#pragma unroll
                for (int n = 0; n < 4; ++n) {
                    int c = n0 + wn * 64 + n * 16 + lc;
                    C[(size_t)r * Ncols + c] = f2bf(acc[m][n][q]);
                }
            }
        }
    }
}

// ---------------- attention coefficients per node ----------------

template<int F, int C>
__global__ void al_kernel(const __hip_bfloat16* __restrict__ h, const float* __restrict__ a_s,
                          const float* __restrict__ a_d, float* __restrict__ als,
                          float* __restrict__ ald, int N) {
    int i = blockIdx.x * blockDim.x + threadIdx.x;
    if (i >= N * 8) return;
    int n = i >> 3, hh = i & 7;
    const ushort* hp = (const ushort*)(h + (size_t)n * F + hh * C);
    const float* asp = a_s + hh * C;
    const float* adp = a_d + hh * C;
    float s = 0.f, dsum = 0.f;
#pragma unroll
    for (int c = 0; c < C; c += 4) {
        ushort4 u = *(const ushort4*)(hp + c);
        float v0 = bf2f(u.x), v1 = bf2f(u.y), v2 = bf2f(u.z), v3 = bf2f(u.w);
        s += v0 * asp[c] + v1 * asp[c + 1] + v2 * asp[c + 2] + v3 * asp[c + 3];
        dsum += v0 * adp[c] + v1 * adp[c + 1] + v2 * adp[c + 2] + v3 * adp[c + 3];
    }
    als[i] = s;
    ald[i] = dsum;
}

// ---------------- per-dst softmax + aggregation ----------------

template<int F, int C>
__global__ __launch_bounds__(F / 2) void aggregate_kernel(const __hip_bfloat16* __restrict__ h,
                                                          const float* __restrict__ als,
                                                          const float* __restrict__ ald,
                                                          const int* __restrict__ offs,
                                                          const int* __restrict__ csr_src,
                                                          const float* __restrict__ bias,
                                                          float* __restrict__ out, int N) {
    constexpr int T = F / 2;
    __shared__ float wl[MAXDEG * 8];
    __shared__ int ssrc[MAXDEG];
    __shared__ float sm[8], sden[8], sald[8];
    int d = blockIdx.x;
    int start = offs[d];
    int deg = offs[d + 1] - start;
    int cdeg = (deg < MAXDEG) ? deg : MAXDEG;
    int tid = threadIdx.x;
    if (tid < 8) sald[tid] = ald[d * 8 + tid];
    for (int e = tid; e < cdeg; e += T) ssrc[e] = csr_src[start + e];
    __syncthreads();
    for (int t = tid; t < cdeg * 8; t += T) {
        int e = t >> 3, hh = t & 7;
        float v = als[ssrc[e] * 8 + hh] + sald[hh];
        v = (v > 0.f) ? v : NEG_SLOPE * v;
        wl[t] = v;
    }
    __syncthreads();
    if (tid < 8) {
        float m = -1e30f;
        for (int e = 0; e < cdeg; ++e) m = fmaxf(m, wl[e * 8 + tid]);
        for (int e = cdeg; e < deg; ++e) {
            int s = csr_src[start + e];
            float v = als[s * 8 + tid] + sald[tid];
            v = (v > 0.f) ? v : NEG_SLOPE * v;
            m = fmaxf(m, v);
        }
        float den = 0.f;
        for (int e = 0; e < cdeg; ++e) {
            float w = __expf(wl[e * 8 + tid] - m);
            wl[e * 8 + tid] = w;
            den += w;
        }
        for (int e = cdeg; e < deg; ++e) {
            int s = csr_src[start + e];
            float v = als[s * 8 + tid] + sald[tid];
            v = (v > 0.f) ? v : NEG_SLOPE * v;
            den += __expf(v - m);
        }
        sm[tid] = m;
        sden[tid] = den;
    }
    __syncthreads();
    int hf = tid / (C / 2);
    float inv = 1.0f / (sden[hf] + 1e-16f);
    float acc0 = 0.f, acc1 = 0.f;
    for (int e = 0; e < cdeg; ++e) {
        float w = wl[e * 8 + hf];
        ushort2 u = *(const ushort2*)((const ushort*)h + (size_t)ssrc[e] * F + 2 * tid);
        acc0 += w * bf2f(u.x);
        acc1 += w * bf2f(u.y);
    }
    for (int e = cdeg; e < deg; ++e) {
        int s = csr_src[start + e];
        float v = als[s * 8 + hf] + sald[hf];
        v = (v > 0.f) ? v : NEG_SLOPE * v;
        float w = __expf(v - sm[hf]);
        ushort2 u = *(const ushort2*)((const ushort*)h + (size_t)s * F + 2 * tid);
        acc0 += w * bf2f(u.x);
        acc1 += w * bf2f(u.y);
    }
    out[(size_t)d * F + 2 * tid]     = acc0 * inv + bias[2 * tid];
    out[(size_t)d * F + 2 * tid + 1] = acc1 * inv + bias[2 * tid + 1];
}

// ---------------- BatchNorm stats ----------------

template<int F>
__global__ __launch_bounds__(256) void bnstats_kernel(const float* __restrict__ x,
                                                      float* __restrict__ bnsum,
                                                      float* __restrict__ bnsq,
                                                      int N, int npb) {
    int n0 = blockIdx.x * npb;
    int n1 = n0 + npb;
    if (n1 > N) n1 = N;
    for (int f = threadIdx.x; f < F; f += 256) {
        float s = 0.f, sq = 0.f;
        for (int n = n0; n < n1; ++n) {
            float v = x[(size_t)n * F + f];
            s += v;
            sq += v * v;
        }
        atomicAdd(&bnsum[f], s);
        atomicAdd(&bnsq[f], sq);
    }
}

template<int F>
__global__ void bnfin_kernel(const float* __restrict__ bnsum, const float* __restrict__ bnsq,
                             const float* __restrict__ g, const float* __restrict__ be,
                             float* __restrict__ scale, float* __restrict__ shift, int N) {
    int f = blockIdx.x * blockDim.x + threadIdx.x;
    if (f >= F) return;
    float invN = 1.0f / (float)N;
    float mean = bnsum[f] * invN;
    float var = bnsq[f] * invN - mean * mean;
    float sc = g[f] * rsqrtf(var + EPS_BN);
    scale[f] = sc;
    shift[f] = be[f] - mean * sc;
}

// ---------------- pooling (BN3+ReLU fused) + FC ----------------

__global__ __launch_bounds__(256) void pool_kernel(const float* __restrict__ x,
                                                   const int* __restrict__ batch,
                                                   const float* __restrict__ scale,
                                                   const float* __restrict__ shift,
                                                   float* __restrict__ pooled, int N) {
    int n0 = blockIdx.x * 64;
    int n1 = n0 + 64;
    if (n1 > N) n1 = N;
    int tid = threadIdx.x;
    float sc0 = scale[tid], sh0 = shift[tid];
    float sc1 = scale[tid + 256], sh1 = shift[tid + 256];
    float m0 = 0.f, m1 = 0.f;
    int cur = -1;
    for (int n = n0; n < n1; ++n) {
        int b = batch[n];
        if (b != cur) {
            if (cur >= 0) {
                atomicMax((int*)&pooled[cur * 512 + tid], __float_as_int(m0));
                atomicMax((int*)&pooled[cur * 512 + tid + 256], __float_as_int(m1));
            }
            cur = b;
            m0 = 0.f;
            m1 = 0.f;
        }
        float v0 = x[(size_t)n * 512 + tid] * sc0 + sh0;
        float v1 = x[(size_t)n * 512 + tid + 256] * sc1 + sh1;
        m0 = fmaxf(m0, v0);
        m1 = fmaxf(m1, v1);
    }
    if (cur >= 0) {
        atomicMax((int*)&pooled[cur * 512 + tid], __float_as_int(m0));
        atomicMax((int*)&pooled[cur * 512 + tid + 256], __float_as_int(m1));
    }
}

__global__ void fc_kernel(const float* __restrict__ pooled, const float* __restrict__ fcW,
                          const float* __restrict__ fcb, float* __restrict__ out) {
    int t = threadIdx.x;
    if (t >= 160) return;
    int b = t / 10, j = t % 10;
    float acc = fcb[j];
    for (int f = 0; f < 512; ++f) acc += pooled[b * 512 + f] * fcW[f * 10 + j];
    out[t] = acc;
}

// ---------------- launch ----------------

extern "C" void kernel_launch(void* const* d_in, const int* in_sizes, int n_in,
                              void* d_out, int out_size, void* d_ws, size_t ws_size,
                              hipStream_t stream) {
    const float* x   = (const float*)d_in[0];
    const int* ei    = (const int*)d_in[1];
    const int* batch = (const int*)d_in[2];
    const float* W1  = (const float*)d_in[3];
    const float* as1 = (const float*)d_in[4];
    const float* ad1 = (const float*)d_in[5];
    const float* b1  = (const float*)d_in[6];
    const float* g1  = (const float*)d_in[7];
    const float* be1 = (const float*)d_in[8];
    const float* W2  = (const float*)d_in[9];
    const float* as2 = (const float*)d_in[10];
    const float* ad2 = (const float*)d_in[11];
    const float* b2  = (const float*)d_in[12];
    const float* g2  = (const float*)d_in[13];
    const float* be2 = (const float*)d_in[14];
    const float* W3  = (const float*)d_in[15];
    const float* as3 = (const float*)d_in[16];
    const float* ad3 = (const float*)d_in[17];
    const float* b3  = (const float*)d_in[18];
    const float* g3  = (const float*)d_in[19];
    const float* be3 = (const float*)d_in[20];
    const float* fcW = (const float*)d_in[21];
    const float* fcb = (const float*)d_in[22];
    float* out = (float*)d_out;

    int N = in_sizes[0] / 3;
    int E = in_sizes[1] / 2;

    char* p = (char*)d_ws;
    auto alloc = [&](size_t bytes) {
        char* r = p;
        p += (bytes + 255) & ~(size_t)255;
        return r;
    };
    int*   counts = (int*)alloc((size_t)N * 4);
    int*   offs   = (int*)alloc((size_t)(N + 1) * 4);
    int*   part   = (int*)alloc(64 * 4);
    int*   csr    = (int*)alloc((size_t)(E + N) * 4);
    __hip_bfloat16* h = (__hip_bfloat16*)alloc((size_t)N * 512 * 2);
    float* agg    = (float*)alloc((size_t)N * 512 * 4);
    ushort* Wt    = (ushort*)alloc(512 * 256 * 2);
    float* als    = (float*)alloc((size_t)N * 8 * 4);
    float* ald    = (float*)alloc((size_t)N * 8 * 4);
    float* bnsum  = (float*)alloc(512 * 4);
    float* bnsq   = (float*)alloc(512 * 4);
    float* scale  = (float*)alloc(512 * 4);
    float* shift  = (float*)alloc(512 * 4);
    float* pooled = (float*)alloc(16 * 512 * 4);
    // GEMM A input lives in the dead upper half of agg: layer-k aggregate uses
    // only N*CIN floats (<= N*256); A is consumed before aggregate overwrites it.
    ushort* Abuf  = (ushort*)(agg + (size_t)N * 256);

    int total_e = E + N;
    int npb = (N + 199) / 200;
    int nchunks = (N + 1023) / 1024;
    int mtiles = (N + 127) / 128;

    // ---- CSR build ----
    hipMemsetAsync(counts, 0, (size_t)N * 4, stream);
    count_kernel<<<(total_e + 255) / 256, 256, 0, stream>>>(ei, E, N, counts);
    scan_block_kernel<<<nchunks, 1024, 0, stream>>>(counts, offs, part, N);
    scan_part_kernel<<<1, 64, 0, stream>>>(part, nchunks);
    scan_add_kernel<<<nchunks, 1024, 0, stream>>>(offs, part, N);
    hipMemsetAsync(counts, 0, (size_t)N * 4, stream);
    scatter_kernel<<<(total_e + 255) / 256, 256, 0, stream>>>(ei, E, N, offs, counts, csr);

    // ---- layer 1: 3 -> 8x16 (F=128) ----
    linear1_kernel<<<(N * 128 + 255) / 256, 256, 0, stream>>>(x, W1, h, N);
    al_kernel<128, 16><<<(N * 8 + 255) / 256, 256, 0, stream>>>(h, as1, ad1, als, ald, N);
    aggregate_kernel<128, 16><<<N, 64, 0, stream>>>(h, als, ald, offs, csr, b1, agg, N);
    hipMemsetAsync(bnsum, 0, 512 * 4, stream);
    hipMemsetAsync(bnsq, 0, 512 * 4, stream);
    bnstats_kernel<128><<<200, 256, 0, stream>>>(agg, bnsum, bnsq, N, npb);
    bnfin_kernel<128><<<1, 128, 0, stream>>>(bnsum, bnsq, g1, be1, scale, shift, N);

    // ---- layer 2: 128 -> 8x32 (F=256), BN1+ReLU folded into prep ----
    transpose_w_kernel<<<(128 / 32) * (256 / 32), 256, 0, stream>>>(W2, Wt, 128, 256);
    prep_kernel<128><<<(N * 128 / 4 + 255) / 256, 256, 0, stream>>>(
        (const float4*)agg, scale, shift, (ushort4*)Abuf, N * 128 / 4);
    mfma_gemm_kernel<128><<<dim3(mtiles, 2), 256, 0, stream>>>(
        Abuf, Wt, (ushort*)h, N, 256);
    al_kernel<256, 32><<<(N * 8 + 255) / 256, 256, 0, stream>>>(h, as2, ad2, als, ald, N);
    aggregate_kernel<256, 32><<<N, 128, 0, stream>>>(h, als, ald, offs, csr, b2, agg, N);
    hipMemsetAsync(bnsum, 0, 512 * 4, stream);
    hipMemsetAsync(bnsq, 0, 512 * 4, stream);
    bnstats_kernel<256><<<200, 256, 0, stream>>>(agg, bnsum, bnsq, N, npb);
    bnfin_kernel<256><<<1, 256, 0, stream>>>(bnsum, bnsq, g2, be2, scale, shift, N);

    // ---- layer 3: 256 -> 8x64 (F=512), BN2+ReLU folded into prep ----
    transpose_w_kernel<<<(256 / 32) * (512 / 32), 256, 0, stream>>>(W3, Wt, 256, 512);
    prep_kernel<256><<<(N * 256 / 4 + 255) / 256, 256, 0, stream>>>(
        (const float4*)agg, scale, shift, (ushort4*)Abuf, N * 256 / 4);
    mfma_gemm_kernel<256><<<dim3(mtiles, 4), 256, 0, stream>>>(
        Abuf, Wt, (ushort*)h, N, 512);
    al_kernel<512, 64><<<(N * 8 + 255) / 256, 256, 0, stream>>>(h, as3, ad3, als, ald, N);
    aggregate_kernel<512, 64><<<N, 256, 0, stream>>>(h, als, ald, offs, csr, b3, agg, N);
    hipMemsetAsync(bnsum, 0, 512 * 4, stream);
    hipMemsetAsync(bnsq, 0, 512 * 4, stream);
    bnstats_kernel<512><<<200, 256, 0, stream>>>(agg, bnsum, bnsq, N, npb);
    bnfin_kernel<512><<<1, 512, 0, stream>>>(bnsum, bnsq, g3, be3, scale, shift, N);

    // ---- pool (BN3+ReLU fused) + fc ----
    hipMemsetAsync(pooled, 0, 16 * 512 * 4, stream);
    pool_kernel<<<(N + 63) / 64, 256, 0, stream>>>(agg, batch, scale, shift, pooled, N);
    fc_kernel<<<1, 192, 0, stream>>>(pooled, fcW, fcb, out);
}